// Round 11
// baseline (1789.472 us; speedup 1.0000x reference)
//
#include <hip/hip_runtime.h>
#include <hip/hip_bf16.h>
#include <math.h>

typedef __bf16 bf16_t;
typedef __bf16 bf16x4 __attribute__((ext_vector_type(4)));
typedef __bf16 bf16x8 __attribute__((ext_vector_type(8)));
typedef float  f32x4  __attribute__((ext_vector_type(4)));
typedef float  f32x16 __attribute__((ext_vector_type(16)));

#define AS1 __attribute__((address_space(1)))
#define AS3 __attribute__((address_space(3)))

__device__ __forceinline__ void gload_lds16(const bf16_t* g, char* l) {
  __builtin_amdgcn_global_load_lds((const AS1 void*)g, (AS3 void*)l, 16, 0, 0);
}

static constexpr int N_ROWS = 8192;
static constexpr int DDIM   = 4096;
static constexpr int KEXP   = 8;
static constexpr int FHID   = 1024;
static constexpr int KD     = 8192;   // inner dim of both GEMMs (2D and K*F)
static constexpr int NKT    = KD / 64; // 128 k-tiles

// ================= packed fragment-major tile format (r10, verified) =================
// Per (256-row block, 64-k tile): 32 KB contiguous; byte layout == GEMM LDS layout.
// A: (R>>7)*16384 + ((k>>4)&3)*4096 + ((R>>5)&3)*1024 + ((k>>3)&1)*512 + (R&31)*16 + (k&7)*2
// B: ((k>>4)&3)*8192 + ((C>>5)&7)*1024 + ((k>>3)&1)*512 + (C&31)*16 + (k&7)*2
// MFMA 32x32x16 operand: lane l = row/col l&31, k-half l>>5 -> lane*16 within 1KB block.

// ---------------- routing: weights = softmax(h_mask @ Wr^T + br) ----------------
__global__ __launch_bounds__(256)
void routing_kernel(const float* __restrict__ hm, const float* __restrict__ Wr,
                    const float* __restrict__ br, float* __restrict__ wgt) {
  const int n = blockIdx.x;
  const int t = threadIdx.x;
  const int wid = t >> 6;
  const float4* row = (const float4*)(hm + (size_t)n * DDIM);
  float4 x[4];
#pragma unroll
  for (int j = 0; j < 4; ++j) x[j] = row[t + j * 256];
  __shared__ float red[KEXP][4];
  float part[KEXP];
#pragma unroll
  for (int k = 0; k < KEXP; ++k) {
    const float4* wr = (const float4*)(Wr + (size_t)k * DDIM);
    float s = 0.f;
#pragma unroll
    for (int j = 0; j < 4; ++j) {
      float4 w4 = wr[t + j * 256];
      s += x[j].x * w4.x + x[j].y * w4.y + x[j].z * w4.z + x[j].w * w4.w;
    }
#pragma unroll
    for (int off = 32; off > 0; off >>= 1) s += __shfl_down(s, off);
    part[k] = s;
  }
  if ((t & 63) == 0) {
#pragma unroll
    for (int k = 0; k < KEXP; ++k) red[k][wid] = part[k];
  }
  __syncthreads();
  if (t == 0) {
    float lg[KEXP];
    float mx = -1e30f;
#pragma unroll
    for (int k = 0; k < KEXP; ++k) {
      lg[k] = red[k][0] + red[k][1] + red[k][2] + red[k][3] + br[k];
      mx = fmaxf(mx, lg[k]);
    }
    float sum = 0.f;
#pragma unroll
    for (int k = 0; k < KEXP; ++k) { lg[k] = expf(lg[k] - mx); sum += lg[k]; }
    float inv = 1.f / sum;
#pragma unroll
    for (int k = 0; k < KEXP; ++k) wgt[(size_t)n * KEXP + k] = lg[k] * inv;
  }
}

// ---------------- pack kernels: fp32 source -> bf16 packed tiles (r10) ----------------
__device__ __forceinline__ bf16x4 cvt4(float4 v) {
  bf16x4 o;
  o[0] = (bf16_t)v.x; o[1] = (bf16_t)v.y; o[2] = (bf16_t)v.z; o[3] = (bf16_t)v.w;
  return o;
}

__global__ __launch_bounds__(256)
void pack_cond_kernel(const float* __restrict__ ha, const float* __restrict__ hm,
                      bf16_t* __restrict__ Apk) {
  const int bm = blockIdx.x >> 7, t = blockIdx.x & 127;
  const int tid = threadIdx.x;
  const float* src = (t < 64) ? ha : hm;
  const int cb = (t & 63) * 64;
  __shared__ char pb[32768];
#pragma unroll
  for (int i = 0; i < 16; ++i) {
    int u = i * 256 + tid;
    int r = u >> 4, c = (u & 15) * 4;
    float4 v = *(const float4*)(src + (size_t)(bm * 256 + r) * DDIM + cb + c);
    int off = ((r >> 7) & 1) * 16384 + ((c >> 4) & 3) * 4096 + ((r >> 5) & 3) * 1024
            + ((c >> 3) & 1) * 512 + (r & 31) * 16 + (c & 7) * 2;
    *(bf16x4*)(pb + off) = cvt4(v);
  }
  __syncthreads();
  char* dst = (char*)Apk + (size_t)blockIdx.x * 32768;
#pragma unroll
  for (int i = 0; i < 8; ++i) {
    int off = i * 4096 + tid * 16;
    *(float4*)(dst + off) = *(const float4*)(pb + off);
  }
}

__global__ __launch_bounds__(256)
void pack_w1_kernel(const float* __restrict__ W1, bf16_t* __restrict__ Bpk) {
  const int bn = blockIdx.x >> 7, t = blockIdx.x & 127;
  const int tid = threadIdx.x;
  __shared__ char pb[32768];
#pragma unroll
  for (int i = 0; i < 16; ++i) {
    int u = i * 256 + tid;
    int r = u >> 4, c = (u & 15) * 4;
    float4 v = *(const float4*)(W1 + (size_t)(bn * 256 + r) * KD + t * 64 + c);
    int off = ((c >> 4) & 3) * 8192 + ((r >> 5) & 7) * 1024
            + ((c >> 3) & 1) * 512 + (r & 31) * 16 + (c & 7) * 2;
    *(bf16x4*)(pb + off) = cvt4(v);
  }
  __syncthreads();
  char* dst = (char*)Bpk + (size_t)blockIdx.x * 32768;
#pragma unroll
  for (int i = 0; i < 8; ++i) {
    int off = i * 4096 + tid * 16;
    *(float4*)(dst + off) = *(const float4*)(pb + off);
  }
}

__global__ __launch_bounds__(256)
void pack_w2_kernel(const float* __restrict__ W2, bf16_t* __restrict__ Bpk) {
  const int bn = blockIdx.x >> 7, t = blockIdx.x & 127;
  const int tid = threadIdx.x;
  const int ke = t >> 4, f0 = (t & 15) * 64;
  __shared__ char pb[32768];
#pragma unroll
  for (int i = 0; i < 16; ++i) {
    int u = i * 256 + tid;
    int r = u >> 4, c = (u & 15) * 4;
    float4 v = *(const float4*)(W2 + ((size_t)ke * DDIM + bn * 256 + r) * FHID + f0 + c);
    int off = ((c >> 4) & 3) * 8192 + ((r >> 5) & 7) * 1024
            + ((c >> 3) & 1) * 512 + (r & 31) * 16 + (c & 7) * 2;
    *(bf16x4*)(pb + off) = cvt4(v);
  }
  __syncthreads();
  char* dst = (char*)Bpk + (size_t)blockIdx.x * 32768;
#pragma unroll
  for (int i = 0; i < 8; ++i) {
    int off = i * 4096 + tid * 16;
    *(float4*)(dst + off) = *(const float4*)(pb + off);
  }
}

// ---------------- 256x256 GEMM v11: 4 waves x 128x128, intra-wave interleave --------
// 1 wave/SIMD (acc 16 x f32x16 = 256 regs; ~340 VGPR total, budget 512). Per k-step
// a wave reads 8 KB (4A+4B) serving 16 MFMA -> per-CU LDS 48 KB/k-step (~420-560cy)
// < MFMA 517cy -> MFMA-bound. In-order issue interleaves next-k-step ds_reads and
// staging gloads into the ~31cy gaps while the next MFMA waits on the busy pipe, so
// reads/stages drain UNDER the burst. Two named frag sets X/Y (rule #20).
// Per tile: 4 bursts, lgkmcnt(0) between; vmcnt(0)+s_barrier once per tile (stages
// issued >=1500cy earlier -> free). s0 reads exposed once/tile (~200cy).
// Buffer safety: reads of buf b retire before the end-of-tile barrier (last LG0);
// stages into buf b issue only in the NEXT tile (after that barrier); data staged
// into b is published by vmcnt(0)+barrier before the tile that reads it. Modular
// tau wrap keeps counts uniform (round-3 lesson).
// MODE 1: +b1, exact GELU, *w[n][expert], store bf16 PACKED (Hpk = GEMM2's A)
// MODE 2: + sum_k w[n][k]*b2[k][col], store fp32 row-major (out)
template <int MODE, int NCOLS>
__global__ __launch_bounds__(256, 1)
void gemm256_kernel(const bf16_t* __restrict__ Apk, const bf16_t* __restrict__ Bpk,
                    void* __restrict__ Cout, const float* __restrict__ bias,
                    const float* __restrict__ wgt) {
  __shared__ char lds_raw[2 * 65536];    // 128 KB

  const int tid  = threadIdx.x;
  const int wid  = tid >> 6;             // 0..3
  const int lane = tid & 63;
  const int wr   = wid >> 1;             // 0..1  (M half)
  const int wc   = wid & 1;              // 0..1  (N half)

  // ---- 2-D concurrency-window block remap (16x16 window, 4x8 per XCD)
  constexpr int NBN    = NCOLS / 256;    // 32 (GEMM1) or 16 (GEMM2)
  constexpr int NWIN_N = NBN / 16;       // 2 or 1
  const int bid = blockIdx.x;
  const int w   = bid >> 8;
  const int sl  = bid & 255;
  const int xcd = sl & 7;
  const int cu  = sl >> 3;
  const int wm  = w / NWIN_N, wn = w % NWIN_N;
  const int bm  = wm * 16 + ((xcd >> 1) << 2) + (cu & 3);
  const int bn  = wn * 16 + ((xcd & 1) << 3) + (cu >> 2);
  const int arow0 = bm * 256;
  const int brow0 = bn * 256;

  // ---- staging: 16 chunks of 4KB/block (1KB per wave per gload)
  const size_t abase = (size_t)bm * NKT * 16384;   // elements
  const size_t bbase = (size_t)bn * NKT * 16384;
  const size_t ssub  = (size_t)(wid * 512 + lane * 8);  // element offset in 4KB chunk
  const int    dsto  = wid << 10;                       // byte offset (wave-uniform)

  // ---- fragment read bases (lane*16 within each 1KB block, conflict-free)
  const char* A0 = lds_raw + wr * 16384 + lane * 16;          // + s*4096 + mi*1024
  const char* B0 = lds_raw + 32768 + wc * 4096 + lane * 16;   // + s*8192 + nj*1024
  const char* A1 = A0 + 65536;
  const char* B1 = B0 + 65536;

  f32x16 acc[4][4];
#pragma unroll
  for (int mi = 0; mi < 4; ++mi)
#pragma unroll
    for (int nj = 0; nj < 4; ++nj)
#pragma unroll
      for (int r = 0; r < 16; ++r) acc[mi][nj][r] = 0.f;

  bf16x8 xa0, xa1, xa2, xa3, xb0, xb1, xb2, xb3;
  bf16x8 ya0, ya1, ya2, ya3, yb0, yb1, yb2, yb3;

#define SB __builtin_amdgcn_sched_barrier(0);
#define LG0 asm volatile("s_waitcnt lgkmcnt(0)" ::: "memory"); SB

#define STGA(C, TAU, NB)                                                         \
  gload_lds16(Apk + abase + (size_t)((TAU) & (NKT - 1)) * 16384 + (C) * 2048 + ssub, \
              (NB) + (C) * 4096 + dsto);
#define STGB(C, TAU, NB)                                                         \
  gload_lds16(Bpk + bbase + (size_t)((TAU) & (NKT - 1)) * 16384 + (C) * 2048 + ssub, \
              (NB) + 32768 + (C) * 4096 + dsto);

#define RDA4(P, BASE, S)                                                        \
  P##a0 = *(const bf16x8*)((BASE) + (S) * 4096);                                \
  P##a1 = *(const bf16x8*)((BASE) + (S) * 4096 + 1024);                         \
  P##a2 = *(const bf16x8*)((BASE) + (S) * 4096 + 2048);                         \
  P##a3 = *(const bf16x8*)((BASE) + (S) * 4096 + 3072);                         \
  SB
#define RDB4(P, BASE, S)                                                        \
  P##b0 = *(const bf16x8*)((BASE) + (S) * 8192);                                \
  P##b1 = *(const bf16x8*)((BASE) + (S) * 8192 + 1024);                         \
  P##b2 = *(const bf16x8*)((BASE) + (S) * 8192 + 2048);                         \
  P##b3 = *(const bf16x8*)((BASE) + (S) * 8192 + 3072);                         \
  SB

#define MF4(P, MI)                                                              \
  acc[MI][0] = __builtin_amdgcn_mfma_f32_32x32x16_bf16(P##a##MI, P##b0,         \
                                                       acc[MI][0], 0, 0, 0);    \
  acc[MI][1] = __builtin_amdgcn_mfma_f32_32x32x16_bf16(P##a##MI, P##b1,         \
                                                       acc[MI][1], 0, 0, 0);    \
  acc[MI][2] = __builtin_amdgcn_mfma_f32_32x32x16_bf16(P##a##MI, P##b2,         \
                                                       acc[MI][2], 0, 0, 0);    \
  acc[MI][3] = __builtin_amdgcn_mfma_f32_32x32x16_bf16(P##a##MI, P##b3,         \
                                                       acc[MI][3], 0, 0, 0);    \
  SB

// One K-tile: 4 k-step bursts. X/Y alternate; next-k reads + stages interleave
// into the MFMA-issue gaps. Ends with vmcnt(0)+barrier (publishes tile T+1).
#define TILE(T, CA, CB, NB)                                                     \
  RDA4(x, CA, 0) RDB4(x, CB, 0)                                                 \
  LG0                                                                           \
  MF4(x, 0) RDA4(y, CA, 1)                                                      \
  MF4(x, 1) RDB4(y, CB, 1)                                                      \
  MF4(x, 2) STGA(0, (T) + 1, NB) STGA(1, (T) + 1, NB)                           \
            STGA(2, (T) + 1, NB) STGA(3, (T) + 1, NB) SB                        \
  MF4(x, 3) STGA(4, (T) + 1, NB) STGA(5, (T) + 1, NB)                           \
            STGA(6, (T) + 1, NB) STGA(7, (T) + 1, NB) SB                        \
  LG0                                                                           \
  MF4(y, 0) RDA4(x, CA, 2)                                                      \
  MF4(y, 1) RDB4(x, CB, 2)                                                      \
  MF4(y, 2) STGB(0, (T) + 1, NB) STGB(1, (T) + 1, NB)                           \
            STGB(2, (T) + 1, NB) STGB(3, (T) + 1, NB) SB                        \
  MF4(y, 3) STGB(4, (T) + 1, NB) STGB(5, (T) + 1, NB)                           \
            STGB(6, (T) + 1, NB) STGB(7, (T) + 1, NB) SB                        \
  LG0                                                                           \
  MF4(x, 0) RDA4(y, CA, 3)                                                      \
  MF4(x, 1) RDB4(y, CB, 3)                                                      \
  MF4(x, 2) MF4(x, 3)                                                           \
  LG0                                                                           \
  MF4(y, 0) MF4(y, 1) MF4(y, 2) MF4(y, 3)                                       \
  asm volatile("s_waitcnt vmcnt(0)" ::: "memory");                              \
  SB                                                                            \
  __builtin_amdgcn_s_barrier();                                                 \
  SB

  // ---- prologue: stage tile 0 into buf0, drain, rendezvous
#pragma unroll
  for (int c = 0; c < 8; ++c) { STGA(c, 0, lds_raw) }
#pragma unroll
  for (int c = 0; c < 8; ++c) { STGB(c, 0, lds_raw) }
  asm volatile("s_waitcnt vmcnt(0)" ::: "memory");
  __builtin_amdgcn_s_barrier();
  SB

  for (int t = 0; t < NKT; t += 2) {
    TILE(t, A0, B0, lds_raw + 65536)
    TILE(t + 1, A1, B1, lds_raw)
  }
#undef TILE
#undef MF4
#undef RDA4
#undef RDB4
#undef STGA
#undef STGB
#undef LG0
#undef SB

  // ---- epilogue.  32x32 C/D layout: col = lane&31, row = (r&3)+8*(r>>2)+4*(lane>>5)
  const int rbase = arow0 + wr * 128 + ((lane >> 5) << 2);
  const int cbase = brow0 + wc * 128 + (lane & 31);

  if constexpr (MODE == 1) {
    // packed H write: element (n,c) -> tile (n>>8, c>>6), A-layout within
    char* __restrict__ Hc = (char*)Cout;
    const int kexp = brow0 >> 10;  // expert is block-uniform (256 | 1024)
    float bv[4];
    size_t cpart[4];
#pragma unroll
    for (int nj = 0; nj < 4; ++nj) {
      int c = cbase + nj * 32;
      bv[nj] = bias[c];
      cpart[nj] = (size_t)(c >> 6) * 32768 + ((c >> 4) & 3) * 4096
                + ((c >> 3) & 1) * 512 + (c & 7) * 2;
    }
#pragma unroll
    for (int mi = 0; mi < 4; ++mi)
#pragma unroll
      for (int r = 0; r < 16; ++r) {
        int n = rbase + mi * 32 + (r & 3) + 8 * (r >> 2);
        float wn4 = wgt[(size_t)n * KEXP + kexp];
        size_t npart = (size_t)(n >> 8) * (NKT * 32768) + ((n >> 7) & 1) * 16384
                     + ((n >> 5) & 3) * 1024 + (n & 31) * 16;
#pragma unroll
        for (int nj = 0; nj < 4; ++nj) {
          float x = acc[mi][nj][r] + bv[nj];
          float g = 0.5f * x * (1.f + erff(x * 0.70710678118654752f));  // exact GELU
          *(bf16_t*)(Hc + npart + cpart[nj]) = (bf16_t)(g * wn4);
        }
      }
  } else {
    float* __restrict__ O = (float*)Cout;
    float bc[4][KEXP];
#pragma unroll
    for (int nj = 0; nj < 4; ++nj)
#pragma unroll
      for (int k = 0; k < KEXP; ++k)
        bc[nj][k] = bias[(size_t)k * NCOLS + cbase + nj * 32];
#pragma unroll
    for (int mi = 0; mi < 4; ++mi)
#pragma unroll
      for (int r = 0; r < 16; ++r) {
        int n = rbase + mi * 32 + (r & 3) + 8 * (r >> 2);
        const float4* wp = (const float4*)(wgt + (size_t)n * KEXP);
        float4 wa = wp[0], wb = wp[1];
        float w8[KEXP] = {wa.x, wa.y, wa.z, wa.w, wb.x, wb.y, wb.z, wb.w};
#pragma unroll
        for (int nj = 0; nj < 4; ++nj) {
          float s = 0.f;
#pragma unroll
          for (int k = 0; k < KEXP; ++k) s += w8[k] * bc[nj][k];
          O[(size_t)n * NCOLS + cbase + nj * 32] = acc[mi][nj][r] + s;
        }
      }
  }
}

extern "C" void kernel_launch(void* const* d_in, const int* in_sizes, int n_in,
                              void* d_out, int out_size, void* d_ws, size_t ws_size,
                              hipStream_t stream) {
  const float* h_anchor = (const float*)d_in[0];
  const float* h_mask   = (const float*)d_in[1];
  const float* Wr       = (const float*)d_in[2];
  const float* br       = (const float*)d_in[3];
  const float* W1       = (const float*)d_in[4];
  const float* b1       = (const float*)d_in[5];
  const float* W2       = (const float*)d_in[6];
  const float* b2       = (const float*)d_in[7];
  float* out = (float*)d_out;

  char* ws = (char*)d_ws;
  bf16_t* Apk  = (bf16_t*)(ws);                       // packed A    128 MB
  bf16_t* B1pk = (bf16_t*)(ws + ((size_t)128 << 20)); // packed W1   128 MB
  bf16_t* B2pk = (bf16_t*)(ws + ((size_t)256 << 20)); // packed W2    64 MB
  bf16_t* Hpk  = (bf16_t*)(ws + ((size_t)320 << 20)); // packed H1s  128 MB
  float*  wgt  = (float*) (ws + ((size_t)448 << 20)); // [8192][8]   256 KB

  routing_kernel<<<N_ROWS, 256, 0, stream>>>(h_mask, Wr, br, wgt);
  pack_cond_kernel<<<32 * 128, 256, 0, stream>>>(h_anchor, h_mask, Apk);
  pack_w1_kernel<<<32 * 128, 256, 0, stream>>>(W1, B1pk);
  pack_w2_kernel<<<16 * 128, 256, 0, stream>>>(W2, B2pk);

  gemm256_kernel<1, 8192><<<(N_ROWS / 256) * (KD / 256), 256, 0, stream>>>(
      Apk, B1pk, (void*)Hpk, b1, wgt);
  gemm256_kernel<2, 4096><<<(N_ROWS / 256) * (DDIM / 256), 256, 0, stream>>>(
      Hpk, B2pk, (void*)out, b2, wgt);
}